// Round 2
// baseline (166.699 us; speedup 1.0000x reference)
//
#include <hip/hip_runtime.h>
#include <hip/hip_bf16.h>

#define N_NODES 8192
#define E_EDGES 16384
#define S_SEG   16
#define EXT     64
#define P_PATHS 2048
#define ROW     1024            // S_SEG*EXT floats per row
#define L_SLOTS 8               // (fallback path) edge slots per slot-group
#define NGROUPS (E_EDGES / L_SLOTS)
#define NWAVES  (NGROUPS * 2)
#define NBLK    (NWAVES / 4)

typedef _Float16 f16x8  __attribute__((ext_vector_type(8)));
typedef _Float16 f16x4  __attribute__((ext_vector_type(4)));
typedef _Float16 half2v __attribute__((ext_vector_type(2)));
typedef float    f32x4  __attribute__((ext_vector_type(4)));

// ---- workspace layout (bytes) ----
#define WS_CMAT  0        // f16[4096]   8 KB
#define WS_HIST  8192     // int[8192]
#define WS_CURS  40960    // int[8192]
#define WS_ROWS  73728    // int[8193]
#define WS_ELIST 106512   // int[16384]  (fallback) / pose (new path)
#define WS_XRS   172048   // int[16384]  (fallback)
#define WS_NDS   237584   // int[16384]  (fallback)
#define WS_OUTE  262144   // f16[E*1024] = 33.55 MB  (new path)
#define OUTE_BYTES ((size_t)E_EDGES * 1024 * 2)

// ---------------------------------------------------------------------------
// shared prep kernels
// ---------------------------------------------------------------------------
__global__ void prep(const int* __restrict__ pidx, const float* __restrict__ pcoef,
                     _Float16* __restrict__ Cmat, int* __restrict__ hist) {
    const int tid = threadIdx.x;
    if (blockIdx.x < 32) { hist[blockIdx.x * 256 + tid] = 0; return; }
    __shared__ float sC[S_SEG * S_SEG * S_SEG];
    for (int i = tid; i < 4096; i += 256) sC[i] = 0.f;
    __syncthreads();
    for (int p = tid; p < P_PATHS; p += 256) {
        int i = pidx[3 * p + 0];
        int j = pidx[3 * p + 1];
        int k = pidx[3 * p + 2];
        atomicAdd(&sC[(k * S_SEG + i) * S_SEG + j], pcoef[p]);
    }
    __syncthreads();
    for (int i = tid; i < 4096; i += 256) Cmat[i] = (_Float16)sC[i];
}

__global__ void hist_k(const int* __restrict__ idx_out, int* __restrict__ hist) {
    const int e = blockIdx.x * 256 + threadIdx.x;
    atomicAdd(&hist[idx_out[e]], 1);
}

__global__ __launch_bounds__(256) void scan_k(const int* __restrict__ hist,
                                              int* __restrict__ rows,
                                              int* __restrict__ cursor) {
    __shared__ int part[256];
    const int t = threadIdx.x;
    const int base = t * 32;
    int loc[32];
    int s = 0;
#pragma unroll
    for (int i = 0; i < 32; ++i) { loc[i] = s; s += hist[base + i]; }
    part[t] = s;
    __syncthreads();
    for (int off = 1; off < 256; off <<= 1) {
        int v = part[t];
        int u = (t >= off) ? part[t - off] : 0;
        __syncthreads();
        part[t] = v + u;
        __syncthreads();
    }
    const int excl = (t == 0) ? 0 : part[t - 1];
#pragma unroll
    for (int i = 0; i < 32; ++i) {
        int v = excl + loc[i];
        rows[base + i] = v;
        cursor[base + i] = v;
    }
    if (t == 255) rows[N_NODES] = part[255];
}

// ---------------------------------------------------------------------------
// NEW PATH: edge-major compute -> sorted f16 out_e workspace -> segmented reduce
// ---------------------------------------------------------------------------
__global__ __launch_bounds__(256) void scatter_pose_k(
        const int* __restrict__ idx_out, int* __restrict__ cursor,
        int* __restrict__ pose) {
    const int e = blockIdx.x * 256 + threadIdx.x;
    const int nd = idx_out[e];
    pose[e] = atomicAdd(&cursor[nd], 1);
}

// One wave per edge, natural edge order (y sequential). Computes the per-edge
// tile out_e[k,c] = sum_{i,j} C[k,i,j] x[idx_in[e],i,c] y[e,j,c] with fp16
// MFMA, then writes it (f16, coalesced via LDS transpose) to the idx_out-sorted
// slot position pose[e] in the workspace.
__global__ __launch_bounds__(256) void p1_edge(
        const float* __restrict__ x, const float* __restrict__ y,
        const _Float16* __restrict__ Cmat,
        const int* __restrict__ idx_in, const int* __restrict__ pose,
        _Float16* __restrict__ oute) {
    __shared__ __attribute__((aligned(16))) _Float16 sx_all[4][ROW];   // 2KB/wave
    __shared__ __attribute__((aligned(16))) half2v   sy_all[4][512];   // 2KB/wave

    const int tid  = threadIdx.x;
    const int lane = tid & 63;
    const int wv   = tid >> 6;
    _Float16* sxh = sx_all[wv];
    half2v*   syp = sy_all[wv];

    const int e   = blockIdx.x * 4 + wv;     // 0..16383
    const int xr  = idx_in[e];
    const int pos = pose[e];

    const int quad = lane >> 4;
    const int m    = lane & 15;
    const int jb2  = (quad & 1) * 4;
    const int ih   = quad >> 1;
    const int jp   = lane >> 3;          // 0..7
    const int cq   = (lane & 7) * 8;     // 8 cols per lane

    // A fragments: afrag[kk][jr] = Cmat[m][kk*32 + quad*8 + jr]
    f16x8 afrag[8];
    {
        const _Float16* basep = Cmat + m * 256 + quad * 8;
#pragma unroll
        for (int kk = 0; kk < 8; ++kk) afrag[kk] = *(const f16x8*)(basep + kk * 32);
    }

    const float* xp = x + (size_t)xr * ROW;
    const float* yp = y + (size_t)e  * ROW;
    float4 xb[4], yb[4];
#pragma unroll
    for (int k4 = 0; k4 < 4; ++k4)
        xb[k4] = *(const float4*)(xp + k4 * 256 + lane * 4);
    yb[0] = *(const float4*)(yp + (2 * jp)     * EXT + cq);
    yb[1] = *(const float4*)(yp + (2 * jp)     * EXT + cq + 4);
    yb[2] = *(const float4*)(yp + (2 * jp + 1) * EXT + cq);
    yb[3] = *(const float4*)(yp + (2 * jp + 1) * EXT + cq + 4);

    // stage -> f16 LDS (wave-private, no barriers)
#pragma unroll
    for (int k4 = 0; k4 < 4; ++k4) {
        const float4 v = xb[k4];
        *(f16x4*)(sxh + k4 * 256 + lane * 4) =
            f16x4{(_Float16)v.x, (_Float16)v.y, (_Float16)v.z, (_Float16)v.w};
    }
    {
        const float4 a0 = yb[0], a1 = yb[1];
        const float4 c0 = yb[2], c1 = yb[3];
        *(f16x8*)(syp + jp * 64 + cq) =
            f16x8{(_Float16)a0.x, (_Float16)c0.x, (_Float16)a0.y, (_Float16)c0.y,
                  (_Float16)a0.z, (_Float16)c0.z, (_Float16)a0.w, (_Float16)c0.w};
        *(f16x8*)(syp + jp * 64 + cq + 4) =
            f16x8{(_Float16)a1.x, (_Float16)c1.x, (_Float16)a1.y, (_Float16)c1.y,
                  (_Float16)a1.z, (_Float16)c1.z, (_Float16)a1.w, (_Float16)c1.w};
    }

    f32x4 acc[4];
#pragma unroll
    for (int ct = 0; ct < 4; ++ct) acc[ct] = f32x4{0.f, 0.f, 0.f, 0.f};

    // 4 col-tiles x 8 K-steps of mfma_f32_16x16x32_f16
#pragma unroll
    for (int ct = 0; ct < 4; ++ct) {
        const int c = ct * 16 + m;
        half2v ypk[4];
#pragma unroll
        for (int r = 0; r < 4; ++r) ypk[r] = syp[(jb2 + r) * 64 + c];
#pragma unroll
        for (int kk = 0; kk < 8; ++kk) {
            const _Float16 xh = sxh[(2 * kk + ih) * EXT + c];
            const half2v hx = {xh, xh};
            const half2v b0 = hx * ypk[0];
            const half2v b1 = hx * ypk[1];
            const half2v b2 = hx * ypk[2];
            const half2v b3 = hx * ypk[3];
            const f16x8 bfrag = {b0[0], b0[1], b1[0], b1[1],
                                 b2[0], b2[1], b3[0], b3[1]};
            acc[ct] = __builtin_amdgcn_mfma_f32_16x16x32_f16(
                          afrag[kk], bfrag, acc[ct], 0, 0, 0);
        }
    }

    // acc -> f16 LDS transpose -> coalesced 16B global stores
#pragma unroll
    for (int ct = 0; ct < 4; ++ct)
#pragma unroll
        for (int r = 0; r < 4; ++r)
            sxh[(quad * 4 + r) * EXT + ct * 16 + m] = (_Float16)acc[ct][r];

    _Float16* op = oute + (size_t)pos * 1024;
    *(f16x8*)(op + lane * 8)       = *(const f16x8*)(sxh + lane * 8);
    *(f16x8*)(op + 512 + lane * 8) = *(const f16x8*)(sxh + 512 + lane * 8);
}

// One wave per output node: slots are contiguous -> sequential f16 reads,
// f32 accumulate, one sequential f32 row write. Covers deg-0 nodes (zeros).
__global__ __launch_bounds__(256) void p2_reduce(
        const _Float16* __restrict__ oute, const int* __restrict__ rows,
        float* __restrict__ out) {
    const int tid  = threadIdx.x;
    const int lane = tid & 63;
    const int wv   = tid >> 6;
    const int n    = blockIdx.x * 4 + wv;    // 0..8191
    const int beg = rows[n], end = rows[n + 1];

    f32x4 acc[4];
#pragma unroll
    for (int q = 0; q < 4; ++q) acc[q] = f32x4{0.f, 0.f, 0.f, 0.f};

    for (int s = beg; s < end; ++s) {
        const _Float16* bp = oute + (size_t)s * 1024;
#pragma unroll
        for (int q = 0; q < 4; ++q) {
            const f16x4 h = *(const f16x4*)(bp + q * 256 + lane * 4);
            acc[q][0] += (float)h[0];
            acc[q][1] += (float)h[1];
            acc[q][2] += (float)h[2];
            acc[q][3] += (float)h[3];
        }
    }
    float* ob = out + (size_t)n * ROW;
#pragma unroll
    for (int q = 0; q < 4; ++q)
        *(f32x4*)(ob + q * 256 + lane * 4) = acc[q];
}

// ---------------------------------------------------------------------------
// FALLBACK PATH (round-1 verified kernels) — used only if ws_size too small
// ---------------------------------------------------------------------------
__global__ __launch_bounds__(256) void scatter_zero_k(
        const int* __restrict__ idx_in, const int* __restrict__ idx_out,
        int* __restrict__ cursor, int* __restrict__ elist,
        int* __restrict__ xrs, int* __restrict__ nds,
        const int* __restrict__ rows, float* __restrict__ out) {
    const int b = blockIdx.x;
    if (b < E_EDGES / 256) {
        const int e = b * 256 + threadIdx.x;
        const int nd = idx_out[e];
        const int pos = atomicAdd(&cursor[nd], 1);
        elist[pos] = e;
        xrs[pos]   = idx_in[e];
        nds[pos]   = nd;
    } else {
        const int n = (b - E_EDGES / 256) * 4 + (threadIdx.x >> 6);
        const int lane = threadIdx.x & 63;
        const int beg = rows[n], end = rows[n + 1];
        const bool need = (beg == end) || ((beg / L_SLOTS) != ((end - 1) / L_SLOTS));
        if (!need) return;
        const float4 z = {0.f, 0.f, 0.f, 0.f};
        float* ob = out + (size_t)n * ROW + lane * 4;
#pragma unroll
        for (int r = 0; r < 4; ++r) *(float4*)(ob + r * 256) = z;
    }
}

__global__ __launch_bounds__(256, 4) void seg_poly_slots(
        const float* __restrict__ x, const float* __restrict__ y,
        const _Float16* __restrict__ Cmat,
        const int* __restrict__ elist, const int* __restrict__ xrs,
        const int* __restrict__ nds, float* __restrict__ out) {
    __shared__ __attribute__((aligned(16))) _Float16 sx_all[4][S_SEG * 32];
    __shared__ __attribute__((aligned(16))) half2v   sy_all[4][8 * 32];

    const int tid  = threadIdx.x;
    const int lane = tid & 63;
    const int wv   = tid >> 6;
    _Float16* sxh = sx_all[wv];
    half2v*   syp = sy_all[wv];

    const int wid = blockIdx.x * 4 + wv;
    const int g   = wid >> 1;
    const int h   = wid & 1;
    const int s0  = g * L_SLOTS;
    const int c0  = h * 32;

    const int quad = lane >> 4;
    const int m    = lane & 15;
    const int jb2  = (quad & 1) * 4;
    const int ih   = quad >> 1;
    const int jp   = lane >> 3;
    const int c4   = (lane & 7) * 4;

    int e_[L_SLOTS], xr_[L_SLOTS], nd_[L_SLOTS];
    {
        int4 a = *(const int4*)(elist + s0); int4 b = *(const int4*)(elist + s0 + 4);
        e_[0]=a.x; e_[1]=a.y; e_[2]=a.z; e_[3]=a.w; e_[4]=b.x; e_[5]=b.y; e_[6]=b.z; e_[7]=b.w;
        a = *(const int4*)(xrs + s0); b = *(const int4*)(xrs + s0 + 4);
        xr_[0]=a.x; xr_[1]=a.y; xr_[2]=a.z; xr_[3]=a.w; xr_[4]=b.x; xr_[5]=b.y; xr_[6]=b.z; xr_[7]=b.w;
        a = *(const int4*)(nds + s0); b = *(const int4*)(nds + s0 + 4);
        nd_[0]=a.x; nd_[1]=a.y; nd_[2]=a.z; nd_[3]=a.w; nd_[4]=b.x; nd_[5]=b.y; nd_[6]=b.z; nd_[7]=b.w;
    }
    const bool prev_same = (s0 > 0)                  && (nds[s0 - 1]       == nd_[0]);
    const bool next_same = (s0 + L_SLOTS < E_EDGES)  && (nds[s0 + L_SLOTS] == nd_[L_SLOTS - 1]);

    f16x8 afrag[8];
    {
        const _Float16* basep = Cmat + m * 256 + quad * 8;
#pragma unroll
        for (int kk = 0; kk < 8; ++kk) afrag[kk] = *(const f16x8*)(basep + kk * 32);
    }

    float4 xbuf[2][2], ybuf[2][2];
    auto issue = [&](int t, int b) {
        const float* xp = x + (size_t)xr_[t] * ROW + c0;
        const float* yp = y + (size_t)e_[t] * ROW + c0;
        xbuf[b][0] = *(const float4*)(xp + jp * EXT + c4);
        xbuf[b][1] = *(const float4*)(xp + (jp + 8) * EXT + c4);
        ybuf[b][0] = *(const float4*)(yp + (2 * jp)     * EXT + c4);
        ybuf[b][1] = *(const float4*)(yp + (2 * jp + 1) * EXT + c4);
    };
    issue(0, 0);
    issue(1, 1);

    f32x4 acc[2];
#pragma unroll
    for (int ct = 0; ct < 2; ++ct) acc[ct] = f32x4{0.f, 0.f, 0.f, 0.f};
    int segStart = 0;

#pragma unroll
    for (int t = 0; t < L_SLOTS; ++t) {
        const int b = t & 1;
        {
            const float4 v0 = xbuf[b][0], v1 = xbuf[b][1];
            *(f16x4*)(sxh + jp * 32 + c4) =
                f16x4{(_Float16)v0.x, (_Float16)v0.y, (_Float16)v0.z, (_Float16)v0.w};
            *(f16x4*)(sxh + (jp + 8) * 32 + c4) =
                f16x4{(_Float16)v1.x, (_Float16)v1.y, (_Float16)v1.z, (_Float16)v1.w};
            const float4 a0 = ybuf[b][0], a1 = ybuf[b][1];
            *(f16x8*)(syp + jp * 32 + c4) =
                f16x8{(_Float16)a0.x, (_Float16)a1.x, (_Float16)a0.y, (_Float16)a1.y,
                      (_Float16)a0.z, (_Float16)a1.z, (_Float16)a0.w, (_Float16)a1.w};
        }
        if (t + 2 < L_SLOTS) issue(t + 2, b);

#pragma unroll
        for (int ct = 0; ct < 2; ++ct) {
            const int cl = ct * 16 + m;
            half2v ypk[4];
#pragma unroll
            for (int r = 0; r < 4; ++r) ypk[r] = syp[(jb2 + r) * 32 + cl];
#pragma unroll
            for (int kk = 0; kk < 8; ++kk) {
                const _Float16 xh = sxh[(2 * kk + ih) * 32 + cl];
                const half2v hx = {xh, xh};
                const half2v b0 = hx * ypk[0];
                const half2v b1 = hx * ypk[1];
                const half2v b2 = hx * ypk[2];
                const half2v b3 = hx * ypk[3];
                const f16x8 bfrag = {b0[0], b0[1], b1[0], b1[1],
                                     b2[0], b2[1], b3[0], b3[1]};
                acc[ct] = __builtin_amdgcn_mfma_f32_16x16x32_f16(
                              afrag[kk], bfrag, acc[ct], 0, 0, 0);
            }
        }

        const bool last = (t == L_SLOTS - 1);
        if (last || nd_[t + 1] != nd_[t]) {
            const bool shared = (segStart == 0 && prev_same) || (last && next_same);
            float* ob = out + (size_t)nd_[t] * ROW + c0;
            if (shared) {
#pragma unroll
                for (int ct = 0; ct < 2; ++ct)
#pragma unroll
                    for (int r = 0; r < 4; ++r)
                        atomicAdd(ob + (quad * 4 + r) * EXT + ct * 16 + m, acc[ct][r]);
            } else {
#pragma unroll
                for (int ct = 0; ct < 2; ++ct)
#pragma unroll
                    for (int r = 0; r < 4; ++r)
                        ob[(quad * 4 + r) * EXT + ct * 16 + m] = acc[ct][r];
            }
#pragma unroll
            for (int ct = 0; ct < 2; ++ct) acc[ct] = f32x4{0.f, 0.f, 0.f, 0.f};
            segStart = t + 1;
        }
    }
}

// ---------------------------------------------------------------------------
extern "C" void kernel_launch(void* const* d_in, const int* in_sizes, int n_in,
                              void* d_out, int out_size, void* d_ws, size_t ws_size,
                              hipStream_t stream) {
    const float* x       = (const float*)d_in[0];
    const float* y       = (const float*)d_in[1];
    const int*   idx_in  = (const int*)d_in[2];
    const int*   idx_out = (const int*)d_in[3];
    const int*   pidx    = (const int*)d_in[4];
    const float* pcoef   = (const float*)d_in[5];
    float* out           = (float*)d_out;

    char* ws = (char*)d_ws;
    _Float16* Cmat = (_Float16*)(ws + WS_CMAT);
    int* hist      = (int*)(ws + WS_HIST);
    int* cursor    = (int*)(ws + WS_CURS);
    int* rows      = (int*)(ws + WS_ROWS);

    if (ws_size >= WS_OUTE + OUTE_BYTES) {
        // streaming two-pass path
        int* pose       = (int*)(ws + WS_ELIST);
        _Float16* oute  = (_Float16*)(ws + WS_OUTE);
        prep<<<33, 256, 0, stream>>>(pidx, pcoef, Cmat, hist);
        hist_k<<<E_EDGES / 256, 256, 0, stream>>>(idx_out, hist);
        scan_k<<<1, 256, 0, stream>>>(hist, rows, cursor);
        scatter_pose_k<<<E_EDGES / 256, 256, 0, stream>>>(idx_out, cursor, pose);
        p1_edge<<<E_EDGES / 4, 256, 0, stream>>>(x, y, Cmat, idx_in, pose, oute);
        p2_reduce<<<N_NODES / 4, 256, 0, stream>>>(oute, rows, out);
    } else {
        // round-1 verified fallback
        int* elist     = (int*)(ws + WS_ELIST);
        int* xrs       = (int*)(ws + WS_XRS);
        int* nds       = (int*)(ws + WS_NDS);
        prep<<<33, 256, 0, stream>>>(pidx, pcoef, Cmat, hist);
        hist_k<<<E_EDGES / 256, 256, 0, stream>>>(idx_out, hist);
        scan_k<<<1, 256, 0, stream>>>(hist, rows, cursor);
        scatter_zero_k<<<E_EDGES / 256 + N_NODES / 4, 256, 0, stream>>>(
            idx_in, idx_out, cursor, elist, xrs, nds, rows, out);
        seg_poly_slots<<<NBLK, 256, 0, stream>>>(x, y, Cmat, elist, xrs, nds, out);
    }
}

// Round 3
// 166.008 us; speedup vs baseline: 1.0042x; 1.0042x over previous
//
#include <hip/hip_runtime.h>
#include <hip/hip_bf16.h>

#define N_NODES 8192
#define E_EDGES 16384
#define S_SEG   16
#define EXT     64
#define P_PATHS 2048
#define ROW     1024            // S_SEG*EXT floats per row
#define L_SLOTS 8               // (fallback path) edge slots per slot-group
#define NGROUPS (E_EDGES / L_SLOTS)
#define NWAVES  (NGROUPS * 2)
#define NBLK    (NWAVES / 4)

typedef _Float16 f16x8  __attribute__((ext_vector_type(8)));
typedef _Float16 f16x4  __attribute__((ext_vector_type(4)));
typedef _Float16 half2v __attribute__((ext_vector_type(2)));
typedef float    f32x4  __attribute__((ext_vector_type(4)));

// ---- workspace layout (bytes) ----
#define WS_CMAT  0        // f16[4096]   8 KB
#define WS_HIST  8192     // int[8192]
#define WS_CURS  40960    // int[8192]
#define WS_ROWS  73728    // int[8193]
#define WS_ELIST 106512   // int[16384]  slot -> edge
#define WS_XRS   172048   // int[16384]  (fallback)
#define WS_NDS   237584   // int[16384]  (fallback)
#define WS_OUTE  262144   // f16[E*1024] = 33.55 MB
#define OUTE_BYTES ((size_t)E_EDGES * 1024 * 2)

// ---------------------------------------------------------------------------
// shared prep kernels
// ---------------------------------------------------------------------------
__global__ void prep(const int* __restrict__ pidx, const float* __restrict__ pcoef,
                     _Float16* __restrict__ Cmat, int* __restrict__ hist) {
    const int tid = threadIdx.x;
    if (blockIdx.x < 32) { hist[blockIdx.x * 256 + tid] = 0; return; }
    __shared__ float sC[S_SEG * S_SEG * S_SEG];
    for (int i = tid; i < 4096; i += 256) sC[i] = 0.f;
    __syncthreads();
    for (int p = tid; p < P_PATHS; p += 256) {
        int i = pidx[3 * p + 0];
        int j = pidx[3 * p + 1];
        int k = pidx[3 * p + 2];
        atomicAdd(&sC[(k * S_SEG + i) * S_SEG + j], pcoef[p]);
    }
    __syncthreads();
    for (int i = tid; i < 4096; i += 256) Cmat[i] = (_Float16)sC[i];
}

__global__ void hist_k(const int* __restrict__ idx_out, int* __restrict__ hist) {
    const int e = blockIdx.x * 256 + threadIdx.x;
    atomicAdd(&hist[idx_out[e]], 1);
}

__global__ __launch_bounds__(256) void scan_k(const int* __restrict__ hist,
                                              int* __restrict__ rows,
                                              int* __restrict__ cursor) {
    __shared__ int part[256];
    const int t = threadIdx.x;
    const int base = t * 32;
    int loc[32];
    int s = 0;
#pragma unroll
    for (int i = 0; i < 32; ++i) { loc[i] = s; s += hist[base + i]; }
    part[t] = s;
    __syncthreads();
    for (int off = 1; off < 256; off <<= 1) {
        int v = part[t];
        int u = (t >= off) ? part[t - off] : 0;
        __syncthreads();
        part[t] = v + u;
        __syncthreads();
    }
    const int excl = (t == 0) ? 0 : part[t - 1];
#pragma unroll
    for (int i = 0; i < 32; ++i) {
        int v = excl + loc[i];
        rows[base + i] = v;
        cursor[base + i] = v;
    }
    if (t == 255) rows[N_NODES] = part[255];
}

// slot -> edge map (idx_out-sorted)
__global__ __launch_bounds__(256) void scatter_elist_k(
        const int* __restrict__ idx_out, int* __restrict__ cursor,
        int* __restrict__ elist) {
    const int e = blockIdx.x * 256 + threadIdx.x;
    const int nd = idx_out[e];
    const int pos = atomicAdd(&cursor[nd], 1);
    elist[pos] = e;
}

// ---------------------------------------------------------------------------
// p1: one wave per edge, NATURAL edge order. y read sequential, x gathered
// (L3-deduped), per-edge tile via fp16 MFMA, result written f16 to oute[e]
// SEQUENTIALLY (2KB/edge). No random HBM writes anywhere.
// ---------------------------------------------------------------------------
__global__ __launch_bounds__(256) void p1_edge(
        const float* __restrict__ x, const float* __restrict__ y,
        const _Float16* __restrict__ Cmat,
        const int* __restrict__ idx_in,
        _Float16* __restrict__ oute) {
    __shared__ __attribute__((aligned(16))) _Float16 sx_all[4][ROW];   // 2KB/wave
    __shared__ __attribute__((aligned(16))) half2v   sy_all[4][512];   // 2KB/wave

    const int tid  = threadIdx.x;
    const int lane = tid & 63;
    const int wv   = tid >> 6;
    _Float16* sxh = sx_all[wv];
    half2v*   syp = sy_all[wv];

    const int e  = blockIdx.x * 4 + wv;     // 0..16383
    const int xr = idx_in[e];

    const int quad = lane >> 4;
    const int m    = lane & 15;
    const int jb2  = (quad & 1) * 4;
    const int ih   = quad >> 1;
    const int jp   = lane >> 3;          // 0..7
    const int cq   = (lane & 7) * 8;     // 8 cols per lane

    // A fragments: afrag[kk][jr] = Cmat[m][kk*32 + quad*8 + jr]
    f16x8 afrag[8];
    {
        const _Float16* basep = Cmat + m * 256 + quad * 8;
#pragma unroll
        for (int kk = 0; kk < 8; ++kk) afrag[kk] = *(const f16x8*)(basep + kk * 32);
    }

    const float* xp = x + (size_t)xr * ROW;
    const float* yp = y + (size_t)e  * ROW;
    float4 xb[4], yb[4];
#pragma unroll
    for (int k4 = 0; k4 < 4; ++k4)
        xb[k4] = *(const float4*)(xp + k4 * 256 + lane * 4);
    yb[0] = *(const float4*)(yp + (2 * jp)     * EXT + cq);
    yb[1] = *(const float4*)(yp + (2 * jp)     * EXT + cq + 4);
    yb[2] = *(const float4*)(yp + (2 * jp + 1) * EXT + cq);
    yb[3] = *(const float4*)(yp + (2 * jp + 1) * EXT + cq + 4);

    // stage -> f16 LDS (wave-private, no barriers)
#pragma unroll
    for (int k4 = 0; k4 < 4; ++k4) {
        const float4 v = xb[k4];
        *(f16x4*)(sxh + k4 * 256 + lane * 4) =
            f16x4{(_Float16)v.x, (_Float16)v.y, (_Float16)v.z, (_Float16)v.w};
    }
    {
        const float4 a0 = yb[0], a1 = yb[1];
        const float4 c0 = yb[2], c1 = yb[3];
        *(f16x8*)(syp + jp * 64 + cq) =
            f16x8{(_Float16)a0.x, (_Float16)c0.x, (_Float16)a0.y, (_Float16)c0.y,
                  (_Float16)a0.z, (_Float16)c0.z, (_Float16)a0.w, (_Float16)c0.w};
        *(f16x8*)(syp + jp * 64 + cq + 4) =
            f16x8{(_Float16)a1.x, (_Float16)c1.x, (_Float16)a1.y, (_Float16)c1.y,
                  (_Float16)a1.z, (_Float16)c1.z, (_Float16)a1.w, (_Float16)c1.w};
    }

    f32x4 acc[4];
#pragma unroll
    for (int ct = 0; ct < 4; ++ct) acc[ct] = f32x4{0.f, 0.f, 0.f, 0.f};

    // 4 col-tiles x 8 K-steps of mfma_f32_16x16x32_f16
#pragma unroll
    for (int ct = 0; ct < 4; ++ct) {
        const int c = ct * 16 + m;
        half2v ypk[4];
#pragma unroll
        for (int r = 0; r < 4; ++r) ypk[r] = syp[(jb2 + r) * 64 + c];
#pragma unroll
        for (int kk = 0; kk < 8; ++kk) {
            const _Float16 xh = sxh[(2 * kk + ih) * EXT + c];
            const half2v hx = {xh, xh};
            const half2v b0 = hx * ypk[0];
            const half2v b1 = hx * ypk[1];
            const half2v b2 = hx * ypk[2];
            const half2v b3 = hx * ypk[3];
            const f16x8 bfrag = {b0[0], b0[1], b1[0], b1[1],
                                 b2[0], b2[1], b3[0], b3[1]};
            acc[ct] = __builtin_amdgcn_mfma_f32_16x16x32_f16(
                          afrag[kk], bfrag, acc[ct], 0, 0, 0);
        }
    }

    // acc -> f16 LDS transpose -> coalesced sequential 16B global stores
#pragma unroll
    for (int ct = 0; ct < 4; ++ct)
#pragma unroll
        for (int r = 0; r < 4; ++r)
            sxh[(quad * 4 + r) * EXT + ct * 16 + m] = (_Float16)acc[ct][r];

    _Float16* op = oute + (size_t)e * 1024;
    *(f16x8*)(op + lane * 8)       = *(const f16x8*)(sxh + lane * 8);
    *(f16x8*)(op + 512 + lane * 8) = *(const f16x8*)(sxh + 512 + lane * 8);
}

// ---------------------------------------------------------------------------
// p2: one wave per output node; contiguous slot range, elist indirection.
// Random 2KB reads hit L3-resident oute; sequential f32 row write.
// Covers deg-0 nodes (writes zeros) -> no zerofill needed.
// ---------------------------------------------------------------------------
__global__ __launch_bounds__(256) void p2_reduce(
        const _Float16* __restrict__ oute, const int* __restrict__ rows,
        const int* __restrict__ elist, float* __restrict__ out) {
    const int tid  = threadIdx.x;
    const int lane = tid & 63;
    const int wv   = tid >> 6;
    const int n    = blockIdx.x * 4 + wv;    // 0..8191
    const int beg = rows[n], end = rows[n + 1];

    f32x4 acc[4];
#pragma unroll
    for (int q = 0; q < 4; ++q) acc[q] = f32x4{0.f, 0.f, 0.f, 0.f};

    for (int s = beg; s < end; ++s) {
        const int e = elist[s];
        const _Float16* bp = oute + (size_t)e * 1024;
        const f16x8 h0 = *(const f16x8*)(bp + lane * 8);
        const f16x8 h1 = *(const f16x8*)(bp + 512 + lane * 8);
#pragma unroll
        for (int i = 0; i < 4; ++i) {
            acc[0][i] += (float)h0[i];
            acc[1][i] += (float)h0[4 + i];
            acc[2][i] += (float)h1[i];
            acc[3][i] += (float)h1[4 + i];
        }
    }
    float* ob = out + (size_t)n * ROW;
    *(f32x4*)(ob + lane * 8)           = acc[0];
    *(f32x4*)(ob + lane * 8 + 4)       = acc[1];
    *(f32x4*)(ob + 512 + lane * 8)     = acc[2];
    *(f32x4*)(ob + 512 + lane * 8 + 4) = acc[3];
}

// ---------------------------------------------------------------------------
// FALLBACK PATH (round-1 verified kernels) — used only if ws_size too small
// ---------------------------------------------------------------------------
__global__ __launch_bounds__(256) void scatter_zero_k(
        const int* __restrict__ idx_in, const int* __restrict__ idx_out,
        int* __restrict__ cursor, int* __restrict__ elist,
        int* __restrict__ xrs, int* __restrict__ nds,
        const int* __restrict__ rows, float* __restrict__ out) {
    const int b = blockIdx.x;
    if (b < E_EDGES / 256) {
        const int e = b * 256 + threadIdx.x;
        const int nd = idx_out[e];
        const int pos = atomicAdd(&cursor[nd], 1);
        elist[pos] = e;
        xrs[pos]   = idx_in[e];
        nds[pos]   = nd;
    } else {
        const int n = (b - E_EDGES / 256) * 4 + (threadIdx.x >> 6);
        const int lane = threadIdx.x & 63;
        const int beg = rows[n], end = rows[n + 1];
        const bool need = (beg == end) || ((beg / L_SLOTS) != ((end - 1) / L_SLOTS));
        if (!need) return;
        const float4 z = {0.f, 0.f, 0.f, 0.f};
        float* ob = out + (size_t)n * ROW + lane * 4;
#pragma unroll
        for (int r = 0; r < 4; ++r) *(float4*)(ob + r * 256) = z;
    }
}

__global__ __launch_bounds__(256, 4) void seg_poly_slots(
        const float* __restrict__ x, const float* __restrict__ y,
        const _Float16* __restrict__ Cmat,
        const int* __restrict__ elist, const int* __restrict__ xrs,
        const int* __restrict__ nds, float* __restrict__ out) {
    __shared__ __attribute__((aligned(16))) _Float16 sx_all[4][S_SEG * 32];
    __shared__ __attribute__((aligned(16))) half2v   sy_all[4][8 * 32];

    const int tid  = threadIdx.x;
    const int lane = tid & 63;
    const int wv   = tid >> 6;
    _Float16* sxh = sx_all[wv];
    half2v*   syp = sy_all[wv];

    const int wid = blockIdx.x * 4 + wv;
    const int g   = wid >> 1;
    const int h   = wid & 1;
    const int s0  = g * L_SLOTS;
    const int c0  = h * 32;

    const int quad = lane >> 4;
    const int m    = lane & 15;
    const int jb2  = (quad & 1) * 4;
    const int ih   = quad >> 1;
    const int jp   = lane >> 3;
    const int c4   = (lane & 7) * 4;

    int e_[L_SLOTS], xr_[L_SLOTS], nd_[L_SLOTS];
    {
        int4 a = *(const int4*)(elist + s0); int4 b = *(const int4*)(elist + s0 + 4);
        e_[0]=a.x; e_[1]=a.y; e_[2]=a.z; e_[3]=a.w; e_[4]=b.x; e_[5]=b.y; e_[6]=b.z; e_[7]=b.w;
        a = *(const int4*)(xrs + s0); b = *(const int4*)(xrs + s0 + 4);
        xr_[0]=a.x; xr_[1]=a.y; xr_[2]=a.z; xr_[3]=a.w; xr_[4]=b.x; xr_[5]=b.y; xr_[6]=b.z; xr_[7]=b.w;
        a = *(const int4*)(nds + s0); b = *(const int4*)(nds + s0 + 4);
        nd_[0]=a.x; nd_[1]=a.y; nd_[2]=a.z; nd_[3]=a.w; nd_[4]=b.x; nd_[5]=b.y; nd_[6]=b.z; nd_[7]=b.w;
    }
    const bool prev_same = (s0 > 0)                  && (nds[s0 - 1]       == nd_[0]);
    const bool next_same = (s0 + L_SLOTS < E_EDGES)  && (nds[s0 + L_SLOTS] == nd_[L_SLOTS - 1]);

    f16x8 afrag[8];
    {
        const _Float16* basep = Cmat + m * 256 + quad * 8;
#pragma unroll
        for (int kk = 0; kk < 8; ++kk) afrag[kk] = *(const f16x8*)(basep + kk * 32);
    }

    float4 xbuf[2][2], ybuf[2][2];
    auto issue = [&](int t, int b) {
        const float* xp = x + (size_t)xr_[t] * ROW + c0;
        const float* yp = y + (size_t)e_[t] * ROW + c0;
        xbuf[b][0] = *(const float4*)(xp + jp * EXT + c4);
        xbuf[b][1] = *(const float4*)(xp + (jp + 8) * EXT + c4);
        ybuf[b][0] = *(const float4*)(yp + (2 * jp)     * EXT + c4);
        ybuf[b][1] = *(const float4*)(yp + (2 * jp + 1) * EXT + c4);
    };
    issue(0, 0);
    issue(1, 1);

    f32x4 acc[2];
#pragma unroll
    for (int ct = 0; ct < 2; ++ct) acc[ct] = f32x4{0.f, 0.f, 0.f, 0.f};
    int segStart = 0;

#pragma unroll
    for (int t = 0; t < L_SLOTS; ++t) {
        const int b = t & 1;
        {
            const float4 v0 = xbuf[b][0], v1 = xbuf[b][1];
            *(f16x4*)(sxh + jp * 32 + c4) =
                f16x4{(_Float16)v0.x, (_Float16)v0.y, (_Float16)v0.z, (_Float16)v0.w};
            *(f16x4*)(sxh + (jp + 8) * 32 + c4) =
                f16x4{(_Float16)v1.x, (_Float16)v1.y, (_Float16)v1.z, (_Float16)v1.w};
            const float4 a0 = ybuf[b][0], a1 = ybuf[b][1];
            *(f16x8*)(syp + jp * 32 + c4) =
                f16x8{(_Float16)a0.x, (_Float16)a1.x, (_Float16)a0.y, (_Float16)a1.y,
                      (_Float16)a0.z, (_Float16)a1.z, (_Float16)a0.w, (_Float16)a1.w};
        }
        if (t + 2 < L_SLOTS) issue(t + 2, b);

#pragma unroll
        for (int ct = 0; ct < 2; ++ct) {
            const int cl = ct * 16 + m;
            half2v ypk[4];
#pragma unroll
            for (int r = 0; r < 4; ++r) ypk[r] = syp[(jb2 + r) * 32 + cl];
#pragma unroll
            for (int kk = 0; kk < 8; ++kk) {
                const _Float16 xh = sxh[(2 * kk + ih) * 32 + cl];
                const half2v hx = {xh, xh};
                const half2v b0 = hx * ypk[0];
                const half2v b1 = hx * ypk[1];
                const half2v b2 = hx * ypk[2];
                const half2v b3 = hx * ypk[3];
                const f16x8 bfrag = {b0[0], b0[1], b1[0], b1[1],
                                     b2[0], b2[1], b3[0], b3[1]};
                acc[ct] = __builtin_amdgcn_mfma_f32_16x16x32_f16(
                              afrag[kk], bfrag, acc[ct], 0, 0, 0);
            }
        }

        const bool last = (t == L_SLOTS - 1);
        if (last || nd_[t + 1] != nd_[t]) {
            const bool shared = (segStart == 0 && prev_same) || (last && next_same);
            float* ob = out + (size_t)nd_[t] * ROW + c0;
            if (shared) {
#pragma unroll
                for (int ct = 0; ct < 2; ++ct)
#pragma unroll
                    for (int r = 0; r < 4; ++r)
                        atomicAdd(ob + (quad * 4 + r) * EXT + ct * 16 + m, acc[ct][r]);
            } else {
#pragma unroll
                for (int ct = 0; ct < 2; ++ct)
#pragma unroll
                    for (int r = 0; r < 4; ++r)
                        ob[(quad * 4 + r) * EXT + ct * 16 + m] = acc[ct][r];
            }
#pragma unroll
            for (int ct = 0; ct < 2; ++ct) acc[ct] = f32x4{0.f, 0.f, 0.f, 0.f};
            segStart = t + 1;
        }
    }
}

// ---------------------------------------------------------------------------
extern "C" void kernel_launch(void* const* d_in, const int* in_sizes, int n_in,
                              void* d_out, int out_size, void* d_ws, size_t ws_size,
                              hipStream_t stream) {
    const float* x       = (const float*)d_in[0];
    const float* y       = (const float*)d_in[1];
    const int*   idx_in  = (const int*)d_in[2];
    const int*   idx_out = (const int*)d_in[3];
    const int*   pidx    = (const int*)d_in[4];
    const float* pcoef   = (const float*)d_in[5];
    float* out           = (float*)d_out;

    char* ws = (char*)d_ws;
    _Float16* Cmat = (_Float16*)(ws + WS_CMAT);
    int* hist      = (int*)(ws + WS_HIST);
    int* cursor    = (int*)(ws + WS_CURS);
    int* rows      = (int*)(ws + WS_ROWS);
    int* elist     = (int*)(ws + WS_ELIST);

    if (ws_size >= WS_OUTE + OUTE_BYTES) {
        // streaming two-pass path: every HBM stream sequential,
        // permutation resolved against L3-resident oute in p2.
        _Float16* oute = (_Float16*)(ws + WS_OUTE);
        prep<<<33, 256, 0, stream>>>(pidx, pcoef, Cmat, hist);
        hist_k<<<E_EDGES / 256, 256, 0, stream>>>(idx_out, hist);
        scan_k<<<1, 256, 0, stream>>>(hist, rows, cursor);
        scatter_elist_k<<<E_EDGES / 256, 256, 0, stream>>>(idx_out, cursor, elist);
        p1_edge<<<E_EDGES / 4, 256, 0, stream>>>(x, y, Cmat, idx_in, oute);
        p2_reduce<<<N_NODES / 4, 256, 0, stream>>>(oute, rows, elist, out);
    } else {
        // round-1 verified fallback
        int* xrs = (int*)(ws + WS_XRS);
        int* nds = (int*)(ws + WS_NDS);
        prep<<<33, 256, 0, stream>>>(pidx, pcoef, Cmat, hist);
        hist_k<<<E_EDGES / 256, 256, 0, stream>>>(idx_out, hist);
        scan_k<<<1, 256, 0, stream>>>(hist, rows, cursor);
        scatter_zero_k<<<E_EDGES / 256 + N_NODES / 4, 256, 0, stream>>>(
            idx_in, idx_out, cursor, elist, xrs, nds, rows, out);
        seg_poly_slots<<<NBLK, 256, 0, stream>>>(x, y, Cmat, elist, xrs, nds, out);
    }
}